// Round 1
// baseline (11132.300 us; speedup 1.0000x reference)
//
#include <hip/hip_runtime.h>

#define TT 2048
#define EE 768
#define HH 512
#define GG 2048   // 4*HH
#define KK 7
#define NEGV -10000.0f
#define TAG_START 5
#define TAG_STOP 6

__device__ __forceinline__ float sigf(float x) { return 1.0f / (1.0f + __expf(-x)); }
__device__ __forceinline__ float tanh_f(float x) { return 1.0f - 2.0f / (__expf(2.0f * x) + 1.0f); }

// ---------------------------------------------------------------------------
// Kernel 1: pre[d][t][R] = embeds[row(t)] . W_ih_d[R] + (b_ih_d[R]+b_hh_d[R])
// dir 0: row(t)=t ; dir 1: row(t)=T-1-t (time-reversed input for backward LSTM)
// 128x128 tile, 8x8 microtile, BK=16. grid (16,16,2), block 256.
// ---------------------------------------------------------------------------
__global__ __launch_bounds__(256) void gemm_pre(
    const float* __restrict__ embeds,
    const float* __restrict__ Wf, const float* __restrict__ bif, const float* __restrict__ bhf,
    const float* __restrict__ Wb, const float* __restrict__ bib, const float* __restrict__ bhb,
    float* __restrict__ pre_f, float* __restrict__ pre_b)
{
    const int dir = blockIdx.z;
    const float* __restrict__ W  = dir ? Wb  : Wf;
    const float* __restrict__ bi = dir ? bib : bif;
    const float* __restrict__ bh = dir ? bhb : bhf;
    float* __restrict__ out = dir ? pre_b : pre_f;
    const int n0 = blockIdx.x * 128;
    const int m0 = blockIdx.y * 128;
    __shared__ __align__(16) float As[16][128];
    __shared__ __align__(16) float Bs[16][128];
    const int tid  = threadIdx.x;
    const int lrow = tid >> 1;     // 0..127
    const int lch  = tid & 1;      // which 8-col half
    const int tx = tid & 15, ty = tid >> 4;
    float acc[8][8];
    #pragma unroll
    for (int i = 0; i < 8; ++i)
        #pragma unroll
        for (int j = 0; j < 8; ++j) acc[i][j] = 0.0f;

    for (int k0 = 0; k0 < EE; k0 += 16) {
        const int am   = m0 + lrow;
        const int arow = dir ? (TT - 1 - am) : am;
        const float4* ap = (const float4*)(embeds + (size_t)arow * EE + k0 + lch * 8);
        const float4 a0 = ap[0], a1 = ap[1];
        const float4* bp = (const float4*)(W + (size_t)(n0 + lrow) * EE + k0 + lch * 8);
        const float4 b0 = bp[0], b1 = bp[1];
        __syncthreads();
        As[lch*8+0][lrow]=a0.x; As[lch*8+1][lrow]=a0.y; As[lch*8+2][lrow]=a0.z; As[lch*8+3][lrow]=a0.w;
        As[lch*8+4][lrow]=a1.x; As[lch*8+5][lrow]=a1.y; As[lch*8+6][lrow]=a1.z; As[lch*8+7][lrow]=a1.w;
        Bs[lch*8+0][lrow]=b0.x; Bs[lch*8+1][lrow]=b0.y; Bs[lch*8+2][lrow]=b0.z; Bs[lch*8+3][lrow]=b0.w;
        Bs[lch*8+4][lrow]=b1.x; Bs[lch*8+5][lrow]=b1.y; Bs[lch*8+6][lrow]=b1.z; Bs[lch*8+7][lrow]=b1.w;
        __syncthreads();
        #pragma unroll
        for (int k = 0; k < 16; ++k) {
            const float4 xa0 = *(const float4*)&As[k][ty*8];
            const float4 xa1 = *(const float4*)&As[k][ty*8+4];
            const float4 xb0 = *(const float4*)&Bs[k][tx*8];
            const float4 xb1 = *(const float4*)&Bs[k][tx*8+4];
            const float av[8] = {xa0.x,xa0.y,xa0.z,xa0.w,xa1.x,xa1.y,xa1.z,xa1.w};
            const float bv[8] = {xb0.x,xb0.y,xb0.z,xb0.w,xb1.x,xb1.y,xb1.z,xb1.w};
            #pragma unroll
            for (int i = 0; i < 8; ++i)
                #pragma unroll
                for (int j = 0; j < 8; ++j)
                    acc[i][j] = fmaf(av[i], bv[j], acc[i][j]);
        }
    }
    float bb[8];
    #pragma unroll
    for (int j = 0; j < 8; ++j) { const int n = n0 + tx*8 + j; bb[j] = bi[n] + bh[n]; }
    #pragma unroll
    for (int i = 0; i < 8; ++i) {
        const int m = m0 + ty*8 + i;
        float4 o0, o1;
        o0.x=acc[i][0]+bb[0]; o0.y=acc[i][1]+bb[1]; o0.z=acc[i][2]+bb[2]; o0.w=acc[i][3]+bb[3];
        o1.x=acc[i][4]+bb[4]; o1.y=acc[i][5]+bb[5]; o1.z=acc[i][6]+bb[6]; o1.w=acc[i][7]+bb[7];
        float4* op = (float4*)(out + (size_t)m * GG + n0 + tx*8);
        op[0] = o0; op[1] = o1;
    }
}

// ---------------------------------------------------------------------------
// Kernel 2: the sequential BiLSTM scan.
// 32 WGs of 512 threads: dir = blockIdx>>4, w = blockIdx&15.
// Each WG owns 128 gate-rows (4 gates x 32 h-indices), W_hh register-resident:
//   wave v owns local rows v*16..v*16+15; lane l holds cols l*8..l*8+7.
// Per step: 128 FMA/lane -> merge-tree 64-lane reduce -> gates on wave0 lanes<32
//   -> write h slice -> device-scope release counter; poll counter of prev step.
// ---------------------------------------------------------------------------
__global__ __launch_bounds__(512) void lstm_scan(
    const float* __restrict__ Whh_f, const float* __restrict__ Whh_b,
    const float* __restrict__ h0, const float* __restrict__ c0,
    const float* __restrict__ pre_f, const float* __restrict__ pre_b,
    float* __restrict__ hs_f, float* __restrict__ hs_b,
    float* __restrict__ hbuf, int* __restrict__ cnt)
{
    const int bx = blockIdx.x;
    const int d = bx >> 4;
    const int w = bx & 15;
    const float* __restrict__ Whh = d ? Whh_b : Whh_f;
    const float* __restrict__ pre = d ? pre_b : pre_f;
    float* __restrict__ hs = d ? hs_b : hs_f;
    float* __restrict__ hb = hbuf + d * 2 * HH;   // ping-pong [2][512] per dir
    int* cn = cnt + (size_t)d * TT * 16;          // padded counters (64B apart)
    const int tid = threadIdx.x;
    const int v = tid >> 6;
    const int l = tid & 63;

    // register-resident W_hh shard: 16 rows x 8 cols = 128 VGPRs
    float wreg[16][8];
    #pragma unroll
    for (int r = 0; r < 16; ++r) {
        const int rho = v * 16 + r;
        const int R = (rho >> 5) * HH + w * 32 + (rho & 31);
        const float4* src = (const float4*)(Whh + (size_t)R * HH + l * 8);
        const float4 w0 = src[0], w1 = src[1];
        wreg[r][0]=w0.x; wreg[r][1]=w0.y; wreg[r][2]=w0.z; wreg[r][3]=w0.w;
        wreg[r][4]=w1.x; wreg[r][5]=w1.y; wreg[r][6]=w1.z; wreg[r][7]=w1.w;
    }
    const bool comb = (v == 0) && (l < 32);
    float creg = comb ? c0[d * HH + w * 32 + l] : 0.0f;
    float hreg[8];
    {
        const float4* hp = (const float4*)(h0 + d * HH + l * 8);
        const float4 ha = hp[0], hc = hp[1];
        hreg[0]=ha.x; hreg[1]=ha.y; hreg[2]=ha.z; hreg[3]=ha.w;
        hreg[4]=hc.x; hreg[5]=hc.y; hreg[6]=hc.z; hreg[7]=hc.w;
    }
    __shared__ float zsum[128];
    // bit-reversed low-4 lane bits -> which row this lane holds after merge-tree
    const int Rl = ((l & 1) << 3) | ((l & 2) << 1) | ((l & 4) >> 1) | ((l & 8) >> 3);
    long long budget = 50000000LL; // hang watchdog: broken sync -> finish w/ garbage, not timeout

    for (int s = 0; s < TT; ++s) {
        // prefetch pre-activations for this step (independent of h) before polling
        float pg0 = 0.f, pg1 = 0.f, pg2 = 0.f, pg3 = 0.f;
        if (comb) {
            const float* pp = pre + (size_t)s * GG + w * 32 + l;
            pg0 = pp[0]; pg1 = pp[HH]; pg2 = pp[2*HH]; pg3 = pp[3*HH];
        }
        if (s > 0) {
            if (tid == 0) {
                while (__hip_atomic_load(cn + (size_t)(s - 1) * 16, __ATOMIC_ACQUIRE,
                                         __HIP_MEMORY_SCOPE_AGENT) < 16) {
                    if (--budget < 0) break;
                    __builtin_amdgcn_s_sleep(1);
                }
            }
            __syncthreads();
            const float4* hp = (const float4*)(hb + (s & 1) * HH + l * 8);
            const float4 ha = hp[0], hc = hp[1];
            hreg[0]=ha.x; hreg[1]=ha.y; hreg[2]=ha.z; hreg[3]=ha.w;
            hreg[4]=hc.x; hreg[5]=hc.y; hreg[6]=hc.z; hreg[7]=hc.w;
        }
        // partial matvec
        float acc[16];
        #pragma unroll
        for (int r = 0; r < 16; ++r) {
            float a = wreg[r][0] * hreg[0];
            #pragma unroll
            for (int i = 1; i < 8; ++i) a = fmaf(wreg[r][i], hreg[i], a);
            acc[r] = a;
        }
        // merge-tree reduction: 16 values over 64 lanes, drop half each stage
        #pragma unroll
        for (int r = 0; r < 16; ++r) acc[r] += __shfl_xor(acc[r], 1);
        float t8[8];
        #pragma unroll
        for (int r = 0; r < 8; ++r) t8[r] = (l & 1) ? acc[8 + r] : acc[r];
        #pragma unroll
        for (int r = 0; r < 8; ++r) t8[r] += __shfl_xor(t8[r], 2);
        float t4[4];
        #pragma unroll
        for (int r = 0; r < 4; ++r) t4[r] = (l & 2) ? t8[4 + r] : t8[r];
        #pragma unroll
        for (int r = 0; r < 4; ++r) t4[r] += __shfl_xor(t4[r], 4);
        float t2[2];
        #pragma unroll
        for (int r = 0; r < 2; ++r) t2[r] = (l & 4) ? t4[2 + r] : t4[r];
        #pragma unroll
        for (int r = 0; r < 2; ++r) t2[r] += __shfl_xor(t2[r], 8);
        float val = (l & 8) ? t2[1] : t2[0];
        val += __shfl_xor(val, 16);
        val += __shfl_xor(val, 32);
        if (l < 16) zsum[v * 16 + Rl] = val;
        __syncthreads();
        if (comb) {
            const float zi = zsum[l]      + pg0;
            const float zf = zsum[32 + l] + pg1;
            const float zg = zsum[64 + l] + pg2;
            const float zo = zsum[96 + l] + pg3;
            const float ig = sigf(zi), fg = sigf(zf), gg = tanh_f(zg), og = sigf(zo);
            creg = fg * creg + ig * gg;
            const float hn = og * tanh_f(creg);
            hb[((s + 1) & 1) * HH + w * 32 + l] = hn;
            hs[(size_t)s * HH + w * 32 + l] = hn;
            __threadfence();   // agent-scope release of h before the flag
        }
        if (tid == 0) {
            __hip_atomic_fetch_add(cn + (size_t)s * 16, 1, __ATOMIC_RELEASE,
                                   __HIP_MEMORY_SCOPE_AGENT);
        }
    }
}

// ---------------------------------------------------------------------------
// Kernel 3: feats[t][k] = [hs_f[t], hs_b[T-1-t]] . W_out[k] + b_out[k]
// one wave per t; 512 blocks x 256 threads.
// ---------------------------------------------------------------------------
__global__ __launch_bounds__(256) void feats_k(
    const float* __restrict__ hsf, const float* __restrict__ hsb,
    const float* __restrict__ Wout, const float* __restrict__ bout,
    float* __restrict__ feats)
{
    const int wv = threadIdx.x >> 6;
    const int l  = threadIdx.x & 63;
    const int t  = blockIdx.x * 4 + wv;
    float acc[KK];
    #pragma unroll
    for (int k = 0; k < KK; ++k) acc[k] = 0.0f;
    const float* hf  = hsf + (size_t)t * HH;
    const float* hbp = hsb + (size_t)(TT - 1 - t) * HH;
    for (int c = l; c < HH; c += 64) {
        const float xf = hf[c];
        const float xb = hbp[c];
        #pragma unroll
        for (int k = 0; k < KK; ++k)
            acc[k] += xf * Wout[k * 1024 + c] + xb * Wout[k * 1024 + HH + c];
    }
    #pragma unroll
    for (int k = 0; k < KK; ++k) {
        #pragma unroll
        for (int m = 1; m <= 32; m <<= 1) acc[k] += __shfl_xor(acc[k], m);
    }
    if (l == 0) {
        #pragma unroll
        for (int k = 0; k < KK; ++k) feats[t * KK + k] = acc[k] + bout[k];
    }
}

// ---------------------------------------------------------------------------
// Kernel 4: Viterbi. 1 block, 64 threads. lane = kn*8+kp (valid kn,kp < 7).
// feats + backpointers + path all in LDS (~74 KB, fine on gfx950's 160 KB).
// Tie-break: first (smallest) index wins, matching jnp.argmax.
// ---------------------------------------------------------------------------
__global__ __launch_bounds__(64) void viterbi_k(
    const float* __restrict__ feats, const float* __restrict__ trans,
    float* __restrict__ out)
{
    __shared__ float fl[TT * KK];
    __shared__ unsigned char bp[TT * KK];
    __shared__ unsigned char path[TT];
    const int l = threadIdx.x;
    for (int i = l; i < TT * KK; i += 64) fl[i] = feats[i];
    const int kn = l >> 3, kp = l & 7;
    const float tr = (kn < 7 && kp < 7) ? trans[kn * 7 + kp] : -1e30f;
    float fv = (kp == 7) ? -1e30f : ((kp == TAG_START) ? 0.0f : NEGV);
    const int srcl = (l & 7) << 3;
    __syncthreads();
    for (int t = 0; t < TT; ++t) {
        float vv = fv + tr;
        int bi = kp;
        #pragma unroll
        for (int m = 1; m <= 4; m <<= 1) {
            const float ov = __shfl_xor(vv, m);
            const int   oi = __shfl_xor(bi, m);
            if (ov > vv || (ov == vv && oi < bi)) { vv = ov; bi = oi; }
        }
        const float feat = fl[t * KK + (kn < 7 ? kn : 6)];
        const float fvn = vv + feat;
        if (kp == 0 && kn < 7) bp[t * KK + kn] = (unsigned char)bi;
        fv = __shfl(fvn, srcl);
        if ((l & 7) == 7) fv = -1e30f;
    }
    float tv = (l < 7) ? (fv + trans[TAG_STOP * 7 + l]) : -1e30f;
    int ti = l & 7;
    #pragma unroll
    for (int m = 1; m <= 4; m <<= 1) {
        const float ov = __shfl_xor(tv, m);
        const int   oi = __shfl_xor(ti, m);
        if (ov > tv || (ov == tv && oi < ti)) { tv = ov; ti = oi; }
    }
    __syncthreads();
    if (l == 0) {
        out[0] = tv;                     // path_score
        int tag = ti;
        path[TT - 1] = (unsigned char)tag;
        for (int t = TT - 1; t >= 1; --t) {
            tag = bp[t * KK + tag];
            path[t - 1] = (unsigned char)tag;
        }
    }
    __syncthreads();
    for (int t = l; t < TT; t += 64) out[1 + t] = (float)path[t];
}

// ---------------------------------------------------------------------------
extern "C" void kernel_launch(void* const* d_in, const int* in_sizes, int n_in,
                              void* d_out, int out_size, void* d_ws, size_t ws_size,
                              hipStream_t stream) {
    const float* embeds = (const float*)d_in[0];
    const float* h0     = (const float*)d_in[1];
    const float* c0     = (const float*)d_in[2];
    const float* Wihf   = (const float*)d_in[3];
    const float* Whhf   = (const float*)d_in[4];
    const float* bihf   = (const float*)d_in[5];
    const float* bhhf   = (const float*)d_in[6];
    const float* Wihb   = (const float*)d_in[7];
    const float* Whhb   = (const float*)d_in[8];
    const float* bihb   = (const float*)d_in[9];
    const float* bhhb   = (const float*)d_in[10];
    const float* Wout   = (const float*)d_in[11];
    const float* bout   = (const float*)d_in[12];
    const float* trans  = (const float*)d_in[13];
    float* out = (float*)d_out;

    float* ws    = (float*)d_ws;
    float* pre_f = ws;                                   // T*G = 4.19M floats
    float* pre_b = pre_f + (size_t)TT * GG;
    float* hs_f  = pre_b + (size_t)TT * GG;              // T*H
    float* hs_b  = hs_f + (size_t)TT * HH;
    float* feats = hs_b + (size_t)TT * HH;               // T*K
    float* hbuf  = feats + (size_t)TT * KK;              // 2*2*H
    int*   cnt   = (int*)(hbuf + 4 * HH);                // 2*T*16 ints

    hipMemsetAsync(cnt, 0, (size_t)2 * TT * 16 * sizeof(int), stream);
    gemm_pre<<<dim3(16, 16, 2), 256, 0, stream>>>(
        embeds, Wihf, bihf, bhhf, Wihb, bihb, bhhb, pre_f, pre_b);
    lstm_scan<<<32, 512, 0, stream>>>(
        Whhf, Whhb, h0, c0, pre_f, pre_b, hs_f, hs_b, hbuf, cnt);
    feats_k<<<TT / 4, 256, 0, stream>>>(hs_f, hs_b, Wout, bout, feats);
    viterbi_k<<<1, 64, 0, stream>>>(feats, trans, out);
}

// Round 3
// 10145.877 us; speedup vs baseline: 1.0972x; 1.0972x over previous
//
#include <hip/hip_runtime.h>

#define TT 2048
#define EE 768
#define HH 512
#define GG 2048   // 4*HH
#define KK 7
#define NEGV -10000.0f
#define TAG_START 5
#define TAG_STOP 6

__device__ __forceinline__ float sigf(float x) { return 1.0f / (1.0f + __expf(-x)); }
__device__ __forceinline__ float tanh_f(float x) { return 1.0f - 2.0f / (__expf(2.0f * x) + 1.0f); }

// ---------------------------------------------------------------------------
// Kernel 1: pre[d][t][R] = embeds[row(t)] . W_ih_d[R] + (b_ih_d[R]+b_hh_d[R])
// ---------------------------------------------------------------------------
__global__ __launch_bounds__(256) void gemm_pre(
    const float* __restrict__ embeds,
    const float* __restrict__ Wf, const float* __restrict__ bif, const float* __restrict__ bhf,
    const float* __restrict__ Wb, const float* __restrict__ bib, const float* __restrict__ bhb,
    float* __restrict__ pre_f, float* __restrict__ pre_b)
{
    const int dir = blockIdx.z;
    const float* __restrict__ W  = dir ? Wb  : Wf;
    const float* __restrict__ bi = dir ? bib : bif;
    const float* __restrict__ bh = dir ? bhb : bhf;
    float* __restrict__ out = dir ? pre_b : pre_f;
    const int n0 = blockIdx.x * 128;
    const int m0 = blockIdx.y * 128;
    __shared__ __align__(16) float As[16][128];
    __shared__ __align__(16) float Bs[16][128];
    const int tid  = threadIdx.x;
    const int lrow = tid >> 1;
    const int lch  = tid & 1;
    const int tx = tid & 15, ty = tid >> 4;
    float acc[8][8];
    #pragma unroll
    for (int i = 0; i < 8; ++i)
        #pragma unroll
        for (int j = 0; j < 8; ++j) acc[i][j] = 0.0f;

    for (int k0 = 0; k0 < EE; k0 += 16) {
        const int am   = m0 + lrow;
        const int arow = dir ? (TT - 1 - am) : am;
        const float4* ap = (const float4*)(embeds + (size_t)arow * EE + k0 + lch * 8);
        const float4 a0 = ap[0], a1 = ap[1];
        const float4* bp = (const float4*)(W + (size_t)(n0 + lrow) * EE + k0 + lch * 8);
        const float4 b0 = bp[0], b1 = bp[1];
        __syncthreads();
        As[lch*8+0][lrow]=a0.x; As[lch*8+1][lrow]=a0.y; As[lch*8+2][lrow]=a0.z; As[lch*8+3][lrow]=a0.w;
        As[lch*8+4][lrow]=a1.x; As[lch*8+5][lrow]=a1.y; As[lch*8+6][lrow]=a1.z; As[lch*8+7][lrow]=a1.w;
        Bs[lch*8+0][lrow]=b0.x; Bs[lch*8+1][lrow]=b0.y; Bs[lch*8+2][lrow]=b0.z; Bs[lch*8+3][lrow]=b0.w;
        Bs[lch*8+4][lrow]=b1.x; Bs[lch*8+5][lrow]=b1.y; Bs[lch*8+6][lrow]=b1.z; Bs[lch*8+7][lrow]=b1.w;
        __syncthreads();
        #pragma unroll
        for (int k = 0; k < 16; ++k) {
            const float4 xa0 = *(const float4*)&As[k][ty*8];
            const float4 xa1 = *(const float4*)&As[k][ty*8+4];
            const float4 xb0 = *(const float4*)&Bs[k][tx*8];
            const float4 xb1 = *(const float4*)&Bs[k][tx*8+4];
            const float av[8] = {xa0.x,xa0.y,xa0.z,xa0.w,xa1.x,xa1.y,xa1.z,xa1.w};
            const float bv[8] = {xb0.x,xb0.y,xb0.z,xb0.w,xb1.x,xb1.y,xb1.z,xb1.w};
            #pragma unroll
            for (int i = 0; i < 8; ++i)
                #pragma unroll
                for (int j = 0; j < 8; ++j)
                    acc[i][j] = fmaf(av[i], bv[j], acc[i][j]);
        }
    }
    float bb[8];
    #pragma unroll
    for (int j = 0; j < 8; ++j) { const int n = n0 + tx*8 + j; bb[j] = bi[n] + bh[n]; }
    #pragma unroll
    for (int i = 0; i < 8; ++i) {
        const int m = m0 + ty*8 + i;
        float4 o0, o1;
        o0.x=acc[i][0]+bb[0]; o0.y=acc[i][1]+bb[1]; o0.z=acc[i][2]+bb[2]; o0.w=acc[i][3]+bb[3];
        o1.x=acc[i][4]+bb[4]; o1.y=acc[i][5]+bb[5]; o1.z=acc[i][6]+bb[6]; o1.w=acc[i][7]+bb[7];
        float4* op = (float4*)(out + (size_t)m * GG + n0 + tx*8);
        op[0] = o0; op[1] = o1;
    }
}

// ---------------------------------------------------------------------------
// Kernel 2: sequential BiLSTM scan. 32 WGs x 512 thr; W_hh register-resident.
// __launch_bounds__(512, 2): 2 waves/EU -> up to 256 VGPR/thread so the
// 128-float wreg shard stays in registers (R1: default bounds capped at 92
// VGPR -> scratch spill -> 1.6 GB of per-step buffer_wbl2 writebacks).
// ---------------------------------------------------------------------------
__global__ __launch_bounds__(512, 2) void lstm_scan(
    const float* __restrict__ Whh_f, const float* __restrict__ Whh_b,
    const float* __restrict__ h0, const float* __restrict__ c0,
    const float* __restrict__ pre_f, const float* __restrict__ pre_b,
    float* __restrict__ hs_f, float* __restrict__ hs_b,
    float* __restrict__ hbuf, int* __restrict__ cnt)
{
    const int bx = blockIdx.x;
    const int d = bx >> 4;
    const int w = bx & 15;
    const float* __restrict__ Whh = d ? Whh_b : Whh_f;
    const float* __restrict__ pre = d ? pre_b : pre_f;
    float* __restrict__ hs = d ? hs_b : hs_f;
    float* __restrict__ hb = hbuf + d * 2 * HH;   // ping-pong [2][512] per dir
    int* cn = cnt + (size_t)d * TT * 32;          // counters 128 B apart
    const int tid = threadIdx.x;
    const int v = tid >> 6;
    const int l = tid & 63;

    // register-resident W_hh shard: 16 rows x 8 cols = 128 VGPRs
    float wreg[16][8];
    #pragma unroll
    for (int r = 0; r < 16; ++r) {
        const int rho = v * 16 + r;
        const int R = (rho >> 5) * HH + w * 32 + (rho & 31);
        const float4* src = (const float4*)(Whh + (size_t)R * HH + l * 8);
        const float4 w0 = src[0], w1 = src[1];
        wreg[r][0]=w0.x; wreg[r][1]=w0.y; wreg[r][2]=w0.z; wreg[r][3]=w0.w;
        wreg[r][4]=w1.x; wreg[r][5]=w1.y; wreg[r][6]=w1.z; wreg[r][7]=w1.w;
    }
    const bool comb = (v == 0) && (l < 32);
    float creg = comb ? c0[d * HH + w * 32 + l] : 0.0f;
    float hreg[8];
    {
        const float4* hp = (const float4*)(h0 + d * HH + l * 8);
        const float4 ha = hp[0], hc = hp[1];
        hreg[0]=ha.x; hreg[1]=ha.y; hreg[2]=ha.z; hreg[3]=ha.w;
        hreg[4]=hc.x; hreg[5]=hc.y; hreg[6]=hc.z; hreg[7]=hc.w;
    }
    __shared__ float zsum[128];
    // bit-reversed low-4 lane bits -> which row this lane holds after merge-tree
    const int Rl = ((l & 1) << 3) | ((l & 2) << 1) | ((l & 4) >> 1) | ((l & 8) >> 3);
    long long budget = 50000000LL; // watchdog: broken sync -> garbage, not hang

    for (int s = 0; s < TT; ++s) {
        // prefetch pre-activations (independent of h) before polling
        float pg0 = 0.f, pg1 = 0.f, pg2 = 0.f, pg3 = 0.f;
        if (comb) {
            const float* pp = pre + (size_t)s * GG + w * 32 + l;
            pg0 = pp[0]; pg1 = pp[HH]; pg2 = pp[2*HH]; pg3 = pp[3*HH];
        }
        if (s > 0) {
            if (tid == 0) {
                while (__hip_atomic_load(cn + (size_t)(s - 1) * 32, __ATOMIC_ACQUIRE,
                                         __HIP_MEMORY_SCOPE_AGENT) < 16) {
                    if (--budget < 0) break;
                    __builtin_amdgcn_s_sleep(1);
                }
            }
            __syncthreads();
            const float4* hp = (const float4*)(hb + (s & 1) * HH + l * 8);
            const float4 ha = hp[0], hc = hp[1];
            hreg[0]=ha.x; hreg[1]=ha.y; hreg[2]=ha.z; hreg[3]=ha.w;
            hreg[4]=hc.x; hreg[5]=hc.y; hreg[6]=hc.z; hreg[7]=hc.w;
        }
        // partial matvec
        float acc[16];
        #pragma unroll
        for (int r = 0; r < 16; ++r) {
            float a = wreg[r][0] * hreg[0];
            #pragma unroll
            for (int i = 1; i < 8; ++i) a = fmaf(wreg[r][i], hreg[i], a);
            acc[r] = a;
        }
        // merge-tree reduction: 16 values over 64 lanes, halve values per stage
        #pragma unroll
        for (int r = 0; r < 16; ++r) acc[r] += __shfl_xor(acc[r], 1);
        float t8[8];
        #pragma unroll
        for (int r = 0; r < 8; ++r) t8[r] = (l & 1) ? acc[8 + r] : acc[r];
        #pragma unroll
        for (int r = 0; r < 8; ++r) t8[r] += __shfl_xor(t8[r], 2);
        float t4[4];
        #pragma unroll
        for (int r = 0; r < 4; ++r) t4[r] = (l & 2) ? t8[4 + r] : t8[r];
        #pragma unroll
        for (int r = 0; r < 4; ++r) t4[r] += __shfl_xor(t4[r], 4);
        float t2[2];
        #pragma unroll
        for (int r = 0; r < 2; ++r) t2[r] = (l & 4) ? t4[2 + r] : t4[r];
        #pragma unroll
        for (int r = 0; r < 2; ++r) t2[r] += __shfl_xor(t2[r], 8);
        float val = (l & 8) ? t2[1] : t2[0];
        val += __shfl_xor(val, 16);
        val += __shfl_xor(val, 32);
        if (l < 16) zsum[v * 16 + Rl] = val;
        __syncthreads();
        if (comb) {
            const float zi = zsum[l]      + pg0;
            const float zf = zsum[32 + l] + pg1;
            const float zg = zsum[64 + l] + pg2;
            const float zo = zsum[96 + l] + pg3;
            const float ig = sigf(zi), fg = sigf(zf), gg = tanh_f(zg), og = sigf(zo);
            creg = fg * creg + ig * gg;
            const float hn = og * tanh_f(creg);
            hb[((s + 1) & 1) * HH + w * 32 + l] = hn;
            hs[(size_t)s * HH + w * 32 + l] = hn;
        }
        if (tid == 0) {
            // RELEASE fetch_add orders wave0's h stores (same wave) before the flag
            __hip_atomic_fetch_add(cn + (size_t)s * 32, 1, __ATOMIC_RELEASE,
                                   __HIP_MEMORY_SCOPE_AGENT);
        }
    }
}

// ---------------------------------------------------------------------------
// Kernel 3: feats[t][k] = [hs_f[t], hs_b[T-1-t]] . W_out[k] + b_out[k]
// ---------------------------------------------------------------------------
__global__ __launch_bounds__(256) void feats_k(
    const float* __restrict__ hsf, const float* __restrict__ hsb,
    const float* __restrict__ Wout, const float* __restrict__ bout,
    float* __restrict__ feats)
{
    const int wv = threadIdx.x >> 6;
    const int l  = threadIdx.x & 63;
    const int t  = blockIdx.x * 4 + wv;
    float acc[KK];
    #pragma unroll
    for (int k = 0; k < KK; ++k) acc[k] = 0.0f;
    const float* hf  = hsf + (size_t)t * HH;
    const float* hbp = hsb + (size_t)(TT - 1 - t) * HH;
    for (int c = l; c < HH; c += 64) {
        const float xf = hf[c];
        const float xb = hbp[c];
        #pragma unroll
        for (int k = 0; k < KK; ++k)
            acc[k] += xf * Wout[k * 1024 + c] + xb * Wout[k * 1024 + HH + c];
    }
    #pragma unroll
    for (int k = 0; k < KK; ++k) {
        #pragma unroll
        for (int m = 1; m <= 32; m <<= 1) acc[k] += __shfl_xor(acc[k], m);
    }
    if (l == 0) {
        #pragma unroll
        for (int k = 0; k < KK; ++k) feats[t * KK + k] = acc[k] + bout[k];
    }
}

// ---------------------------------------------------------------------------
// Kernel 4: Viterbi. 1 block, 64 threads. lane = kn*8+kp (valid kn,kp < 7).
// ---------------------------------------------------------------------------
__global__ __launch_bounds__(64) void viterbi_k(
    const float* __restrict__ feats, const float* __restrict__ trans,
    float* __restrict__ out)
{
    __shared__ float fl[TT * KK];
    __shared__ unsigned char bp[TT * KK];
    __shared__ unsigned char path[TT];
    const int l = threadIdx.x;
    for (int i = l; i < TT * KK; i += 64) fl[i] = feats[i];
    const int kn = l >> 3, kp = l & 7;
    const float tr = (kn < 7 && kp < 7) ? trans[kn * 7 + kp] : -1e30f;
    float fv = (kp == 7) ? -1e30f : ((kp == TAG_START) ? 0.0f : NEGV);
    const int srcl = (l & 7) << 3;
    __syncthreads();
    for (int t = 0; t < TT; ++t) {
        float vv = fv + tr;
        int bi = kp;
        #pragma unroll
        for (int m = 1; m <= 4; m <<= 1) {
            const float ov = __shfl_xor(vv, m);
            const int   oi = __shfl_xor(bi, m);
            if (ov > vv || (ov == vv && oi < bi)) { vv = ov; bi = oi; }
        }
        const float feat = fl[t * KK + (kn < 7 ? kn : 6)];
        const float fvn = vv + feat;
        if (kp == 0 && kn < 7) bp[t * KK + kn] = (unsigned char)bi;
        fv = __shfl(fvn, srcl);
        if ((l & 7) == 7) fv = -1e30f;
    }
    float tv = (l < 7) ? (fv + trans[TAG_STOP * 7 + l]) : -1e30f;
    int ti = l & 7;
    #pragma unroll
    for (int m = 1; m <= 4; m <<= 1) {
        const float ov = __shfl_xor(tv, m);
        const int   oi = __shfl_xor(ti, m);
        if (ov > tv || (ov == tv && oi < ti)) { tv = ov; ti = oi; }
    }
    __syncthreads();
    if (l == 0) {
        out[0] = tv;                     // path_score
        int tag = ti;
        path[TT - 1] = (unsigned char)tag;
        for (int t = TT - 1; t >= 1; --t) {
            tag = bp[t * KK + tag];
            path[t - 1] = (unsigned char)tag;
        }
    }
    __syncthreads();
    for (int t = l; t < TT; t += 64) out[1 + t] = (float)path[t];
}

// ---------------------------------------------------------------------------
extern "C" void kernel_launch(void* const* d_in, const int* in_sizes, int n_in,
                              void* d_out, int out_size, void* d_ws, size_t ws_size,
                              hipStream_t stream) {
    const float* embeds = (const float*)d_in[0];
    const float* h0     = (const float*)d_in[1];
    const float* c0     = (const float*)d_in[2];
    const float* Wihf   = (const float*)d_in[3];
    const float* Whhf   = (const float*)d_in[4];
    const float* bihf   = (const float*)d_in[5];
    const float* bhhf   = (const float*)d_in[6];
    const float* Wihb   = (const float*)d_in[7];
    const float* Whhb   = (const float*)d_in[8];
    const float* bihb   = (const float*)d_in[9];
    const float* bhhb   = (const float*)d_in[10];
    const float* Wout   = (const float*)d_in[11];
    const float* bout   = (const float*)d_in[12];
    const float* trans  = (const float*)d_in[13];
    float* out = (float*)d_out;

    float* ws    = (float*)d_ws;
    float* pre_f = ws;                                   // T*G floats
    float* pre_b = pre_f + (size_t)TT * GG;
    float* hs_f  = pre_b + (size_t)TT * GG;              // T*H
    float* hs_b  = hs_f + (size_t)TT * HH;
    float* feats = hs_b + (size_t)TT * HH;               // T*K
    float* hbuf  = feats + (size_t)TT * KK;              // 2*2*H
    int*   cnt   = (int*)(hbuf + 4 * HH);                // 2*T*32 ints

    hipMemsetAsync(cnt, 0, (size_t)2 * TT * 32 * sizeof(int), stream);
    gemm_pre<<<dim3(16, 16, 2), 256, 0, stream>>>(
        embeds, Wihf, bihf, bhhf, Wihb, bihb, bhhb, pre_f, pre_b);
    lstm_scan<<<32, 512, 0, stream>>>(
        Whhf, Whhb, h0, c0, pre_f, pre_b, hs_f, hs_b, hbuf, cnt);
    feats_k<<<TT / 4, 256, 0, stream>>>(hs_f, hs_b, Wout, bout, feats);
    viterbi_k<<<1, 64, 0, stream>>>(feats, trans, out);
}

// Round 4
// 8287.018 us; speedup vs baseline: 1.3433x; 1.2243x over previous
//
#include <hip/hip_runtime.h>

#define TT 2048
#define EE 768
#define HH 512
#define GG 2048   // 4*HH
#define KK 7
#define NEGV -10000.0f
#define TAG_START 5
#define TAG_STOP 6

__device__ __forceinline__ float sigf(float x) { return 1.0f / (1.0f + __expf(-x)); }
__device__ __forceinline__ float tanh_f(float x) { return 1.0f - 2.0f / (__expf(2.0f * x) + 1.0f); }

// ---------------------------------------------------------------------------
// Kernel 1: pre[d][t][R] = embeds[row(t)] . W_ih_d[R] + (b_ih_d[R]+b_hh_d[R])
// ---------------------------------------------------------------------------
__global__ __launch_bounds__(256) void gemm_pre(
    const float* __restrict__ embeds,
    const float* __restrict__ Wf, const float* __restrict__ bif, const float* __restrict__ bhf,
    const float* __restrict__ Wb, const float* __restrict__ bib, const float* __restrict__ bhb,
    float* __restrict__ pre_f, float* __restrict__ pre_b)
{
    const int dir = blockIdx.z;
    const float* __restrict__ W  = dir ? Wb  : Wf;
    const float* __restrict__ bi = dir ? bib : bif;
    const float* __restrict__ bh = dir ? bhb : bhf;
    float* __restrict__ out = dir ? pre_b : pre_f;
    const int n0 = blockIdx.x * 128;
    const int m0 = blockIdx.y * 128;
    __shared__ __align__(16) float As[16][128];
    __shared__ __align__(16) float Bs[16][128];
    const int tid  = threadIdx.x;
    const int lrow = tid >> 1;
    const int lch  = tid & 1;
    const int tx = tid & 15, ty = tid >> 4;
    float acc[8][8];
    #pragma unroll
    for (int i = 0; i < 8; ++i)
        #pragma unroll
        for (int j = 0; j < 8; ++j) acc[i][j] = 0.0f;

    for (int k0 = 0; k0 < EE; k0 += 16) {
        const int am   = m0 + lrow;
        const int arow = dir ? (TT - 1 - am) : am;
        const float4* ap = (const float4*)(embeds + (size_t)arow * EE + k0 + lch * 8);
        const float4 a0 = ap[0], a1 = ap[1];
        const float4* bp = (const float4*)(W + (size_t)(n0 + lrow) * EE + k0 + lch * 8);
        const float4 b0 = bp[0], b1 = bp[1];
        __syncthreads();
        As[lch*8+0][lrow]=a0.x; As[lch*8+1][lrow]=a0.y; As[lch*8+2][lrow]=a0.z; As[lch*8+3][lrow]=a0.w;
        As[lch*8+4][lrow]=a1.x; As[lch*8+5][lrow]=a1.y; As[lch*8+6][lrow]=a1.z; As[lch*8+7][lrow]=a1.w;
        Bs[lch*8+0][lrow]=b0.x; Bs[lch*8+1][lrow]=b0.y; Bs[lch*8+2][lrow]=b0.z; Bs[lch*8+3][lrow]=b0.w;
        Bs[lch*8+4][lrow]=b1.x; Bs[lch*8+5][lrow]=b1.y; Bs[lch*8+6][lrow]=b1.z; Bs[lch*8+7][lrow]=b1.w;
        __syncthreads();
        #pragma unroll
        for (int k = 0; k < 16; ++k) {
            const float4 xa0 = *(const float4*)&As[k][ty*8];
            const float4 xa1 = *(const float4*)&As[k][ty*8+4];
            const float4 xb0 = *(const float4*)&Bs[k][tx*8];
            const float4 xb1 = *(const float4*)&Bs[k][tx*8+4];
            const float av[8] = {xa0.x,xa0.y,xa0.z,xa0.w,xa1.x,xa1.y,xa1.z,xa1.w};
            const float bv[8] = {xb0.x,xb0.y,xb0.z,xb0.w,xb1.x,xb1.y,xb1.z,xb1.w};
            #pragma unroll
            for (int i = 0; i < 8; ++i)
                #pragma unroll
                for (int j = 0; j < 8; ++j)
                    acc[i][j] = fmaf(av[i], bv[j], acc[i][j]);
        }
    }
    float bb[8];
    #pragma unroll
    for (int j = 0; j < 8; ++j) { const int n = n0 + tx*8 + j; bb[j] = bi[n] + bh[n]; }
    #pragma unroll
    for (int i = 0; i < 8; ++i) {
        const int m = m0 + ty*8 + i;
        float4 o0, o1;
        o0.x=acc[i][0]+bb[0]; o0.y=acc[i][1]+bb[1]; o0.z=acc[i][2]+bb[2]; o0.w=acc[i][3]+bb[3];
        o1.x=acc[i][4]+bb[4]; o1.y=acc[i][5]+bb[5]; o1.z=acc[i][6]+bb[6]; o1.w=acc[i][7]+bb[7];
        float4* op = (float4*)(out + (size_t)m * GG + n0 + tx*8);
        op[0] = o0; op[1] = o1;
    }
}

// ---------------------------------------------------------------------------
// Kernel 2: sequential BiLSTM scan.
// 64 WGs x 512 thr: dir = bx>>5, w = bx&31. Each WG owns 64 gate-rows
// (4 gates x 16 h-indices): global row R = g*512 + w*16 + j, local rho=g*16+j.
// Wave v holds rows rho = v*8..v*8+7; lane l holds cols l*8..l*8+7.
// wreg = 8x8 = 64 floats/thread (~110 VGPR total) so even a conservative
// 128-reg budget fits with NO spill (R1/R3: 128-float shard spilled to
// LDS+scratch -> 1.6 GB/dispatch writeback, 6.3e7 LDS conflicts).
// amdgpu_waves_per_eu(1,2) additionally raises the budget directly.
// ---------------------------------------------------------------------------
__global__ void __launch_bounds__(512)
__attribute__((amdgpu_waves_per_eu(1, 2)))
lstm_scan(
    const float* __restrict__ Whh_f, const float* __restrict__ Whh_b,
    const float* __restrict__ h0, const float* __restrict__ c0,
    const float* __restrict__ pre_f, const float* __restrict__ pre_b,
    float* __restrict__ hs_f, float* __restrict__ hs_b,
    float* __restrict__ hbuf, int* __restrict__ cnt)
{
    const int bx = blockIdx.x;
    const int d = bx >> 5;
    const int w = bx & 31;
    const float* __restrict__ Whh = d ? Whh_b : Whh_f;
    const float* __restrict__ pre = d ? pre_b : pre_f;
    float* __restrict__ hs = d ? hs_b : hs_f;
    float* __restrict__ hb = hbuf + d * 2 * HH;   // ping-pong [2][512] per dir
    int* cn = cnt + (size_t)d * TT * 32;          // counters 128 B apart
    const int tid = threadIdx.x;
    const int v = tid >> 6;
    const int l = tid & 63;

    // register-resident W_hh shard: 8 rows x 8 cols = 64 VGPRs
    float wreg[8][8];
    #pragma unroll
    for (int r = 0; r < 8; ++r) {
        const int rho = v * 8 + r;                       // 0..63
        const int R = (rho >> 4) * HH + w * 16 + (rho & 15);
        const float4* src = (const float4*)(Whh + (size_t)R * HH + l * 8);
        const float4 w0 = src[0], w1 = src[1];
        wreg[r][0]=w0.x; wreg[r][1]=w0.y; wreg[r][2]=w0.z; wreg[r][3]=w0.w;
        wreg[r][4]=w1.x; wreg[r][5]=w1.y; wreg[r][6]=w1.z; wreg[r][7]=w1.w;
    }
    const bool comb = (v == 0) && (l < 16);
    float creg = comb ? c0[d * HH + w * 16 + l] : 0.0f;
    float hreg[8];
    {
        const float4* hp = (const float4*)(h0 + d * HH + l * 8);
        const float4 ha = hp[0], hc = hp[1];
        hreg[0]=ha.x; hreg[1]=ha.y; hreg[2]=ha.z; hreg[3]=ha.w;
        hreg[4]=hc.x; hreg[5]=hc.y; hreg[6]=hc.z; hreg[7]=hc.w;
    }
    __shared__ float zsum[64];
    // bit-reversed low-3 lane bits -> which row this lane holds after merge-tree
    const int Rl = ((l & 1) << 2) | (l & 2) | ((l & 4) >> 2);
    long long budget = 50000000LL; // watchdog: broken sync -> garbage, not hang

    for (int s = 0; s < TT; ++s) {
        // prefetch pre-activations (independent of h) before polling
        float pg0 = 0.f, pg1 = 0.f, pg2 = 0.f, pg3 = 0.f;
        if (comb) {
            const float* pp = pre + (size_t)s * GG + w * 16 + l;
            pg0 = pp[0]; pg1 = pp[HH]; pg2 = pp[2*HH]; pg3 = pp[3*HH];
        }
        if (s > 0) {
            if (tid == 0) {
                while (__hip_atomic_load(cn + (size_t)(s - 1) * 32, __ATOMIC_ACQUIRE,
                                         __HIP_MEMORY_SCOPE_AGENT) < 32) {
                    if (--budget < 0) break;
                    __builtin_amdgcn_s_sleep(1);
                }
            }
            __syncthreads();
            const float4* hp = (const float4*)(hb + (s & 1) * HH + l * 8);
            const float4 ha = hp[0], hc = hp[1];
            hreg[0]=ha.x; hreg[1]=ha.y; hreg[2]=ha.z; hreg[3]=ha.w;
            hreg[4]=hc.x; hreg[5]=hc.y; hreg[6]=hc.z; hreg[7]=hc.w;
        }
        // partial matvec: 64 FMA/lane
        float acc[8];
        #pragma unroll
        for (int r = 0; r < 8; ++r) {
            float a = wreg[r][0] * hreg[0];
            #pragma unroll
            for (int i = 1; i < 8; ++i) a = fmaf(wreg[r][i], hreg[i], a);
            acc[r] = a;
        }
        // merge-tree reduction: 8 values over 64 lanes
        #pragma unroll
        for (int r = 0; r < 8; ++r) acc[r] += __shfl_xor(acc[r], 1);
        float t4[4];
        #pragma unroll
        for (int r = 0; r < 4; ++r) t4[r] = (l & 1) ? acc[4 + r] : acc[r];
        #pragma unroll
        for (int r = 0; r < 4; ++r) t4[r] += __shfl_xor(t4[r], 2);
        float t2[2];
        #pragma unroll
        for (int r = 0; r < 2; ++r) t2[r] = (l & 2) ? t4[2 + r] : t4[r];
        #pragma unroll
        for (int r = 0; r < 2; ++r) t2[r] += __shfl_xor(t2[r], 4);
        float val = (l & 4) ? t2[1] : t2[0];
        val += __shfl_xor(val, 8);
        val += __shfl_xor(val, 16);
        val += __shfl_xor(val, 32);
        if (l < 8) zsum[v * 8 + Rl] = val;
        __syncthreads();
        if (comb) {
            const float zi = zsum[l]      + pg0;
            const float zf = zsum[16 + l] + pg1;
            const float zg = zsum[32 + l] + pg2;
            const float zo = zsum[48 + l] + pg3;
            const float ig = sigf(zi), fg = sigf(zf), gg = tanh_f(zg), og = sigf(zo);
            creg = fg * creg + ig * gg;
            const float hn = og * tanh_f(creg);
            hb[((s + 1) & 1) * HH + w * 16 + l] = hn;
            hs[(size_t)s * HH + w * 16 + l] = hn;
        }
        if (tid == 0) {
            // RELEASE fetch_add orders wave0's h stores (same wave) before the flag
            __hip_atomic_fetch_add(cn + (size_t)s * 32, 1, __ATOMIC_RELEASE,
                                   __HIP_MEMORY_SCOPE_AGENT);
        }
    }
}

// ---------------------------------------------------------------------------
// Kernel 3: feats[t][k] = [hs_f[t], hs_b[T-1-t]] . W_out[k] + b_out[k]
// ---------------------------------------------------------------------------
__global__ __launch_bounds__(256) void feats_k(
    const float* __restrict__ hsf, const float* __restrict__ hsb,
    const float* __restrict__ Wout, const float* __restrict__ bout,
    float* __restrict__ feats)
{
    const int wv = threadIdx.x >> 6;
    const int l  = threadIdx.x & 63;
    const int t  = blockIdx.x * 4 + wv;
    float acc[KK];
    #pragma unroll
    for (int k = 0; k < KK; ++k) acc[k] = 0.0f;
    const float* hf  = hsf + (size_t)t * HH;
    const float* hbp = hsb + (size_t)(TT - 1 - t) * HH;
    for (int c = l; c < HH; c += 64) {
        const float xf = hf[c];
        const float xb = hbp[c];
        #pragma unroll
        for (int k = 0; k < KK; ++k)
            acc[k] += xf * Wout[k * 1024 + c] + xb * Wout[k * 1024 + HH + c];
    }
    #pragma unroll
    for (int k = 0; k < KK; ++k) {
        #pragma unroll
        for (int m = 1; m <= 32; m <<= 1) acc[k] += __shfl_xor(acc[k], m);
    }
    if (l == 0) {
        #pragma unroll
        for (int k = 0; k < KK; ++k) feats[t * KK + k] = acc[k] + bout[k];
    }
}

// ---------------------------------------------------------------------------
// Kernel 4: Viterbi. 1 block, 64 threads. lane = kn*8+kp (valid kn,kp < 7).
// ---------------------------------------------------------------------------
__global__ __launch_bounds__(64) void viterbi_k(
    const float* __restrict__ feats, const float* __restrict__ trans,
    float* __restrict__ out)
{
    __shared__ float fl[TT * KK];
    __shared__ unsigned char bp[TT * KK];
    __shared__ unsigned char path[TT];
    const int l = threadIdx.x;
    for (int i = l; i < TT * KK; i += 64) fl[i] = feats[i];
    const int kn = l >> 3, kp = l & 7;
    const float tr = (kn < 7 && kp < 7) ? trans[kn * 7 + kp] : -1e30f;
    float fv = (kp == 7) ? -1e30f : ((kp == TAG_START) ? 0.0f : NEGV);
    const int srcl = (l & 7) << 3;
    __syncthreads();
    for (int t = 0; t < TT; ++t) {
        float vv = fv + tr;
        int bi = kp;
        #pragma unroll
        for (int m = 1; m <= 4; m <<= 1) {
            const float ov = __shfl_xor(vv, m);
            const int   oi = __shfl_xor(bi, m);
            if (ov > vv || (ov == vv && oi < bi)) { vv = ov; bi = oi; }
        }
        const float feat = fl[t * KK + (kn < 7 ? kn : 6)];
        const float fvn = vv + feat;
        if (kp == 0 && kn < 7) bp[t * KK + kn] = (unsigned char)bi;
        fv = __shfl(fvn, srcl);
        if ((l & 7) == 7) fv = -1e30f;
    }
    float tv = (l < 7) ? (fv + trans[TAG_STOP * 7 + l]) : -1e30f;
    int ti = l & 7;
    #pragma unroll
    for (int m = 1; m <= 4; m <<= 1) {
        const float ov = __shfl_xor(tv, m);
        const int   oi = __shfl_xor(ti, m);
        if (ov > tv || (ov == tv && oi < ti)) { tv = ov; ti = oi; }
    }
    __syncthreads();
    if (l == 0) {
        out[0] = tv;                     // path_score
        int tag = ti;
        path[TT - 1] = (unsigned char)tag;
        for (int t = TT - 1; t >= 1; --t) {
            tag = bp[t * KK + tag];
            path[t - 1] = (unsigned char)tag;
        }
    }
    __syncthreads();
    for (int t = l; t < TT; t += 64) out[1 + t] = (float)path[t];
}

// ---------------------------------------------------------------------------
extern "C" void kernel_launch(void* const* d_in, const int* in_sizes, int n_in,
                              void* d_out, int out_size, void* d_ws, size_t ws_size,
                              hipStream_t stream) {
    const float* embeds = (const float*)d_in[0];
    const float* h0     = (const float*)d_in[1];
    const float* c0     = (const float*)d_in[2];
    const float* Wihf   = (const float*)d_in[3];
    const float* Whhf   = (const float*)d_in[4];
    const float* bihf   = (const float*)d_in[5];
    const float* bhhf   = (const float*)d_in[6];
    const float* Wihb   = (const float*)d_in[7];
    const float* Whhb   = (const float*)d_in[8];
    const float* bihb   = (const float*)d_in[9];
    const float* bhhb   = (const float*)d_in[10];
    const float* Wout   = (const float*)d_in[11];
    const float* bout   = (const float*)d_in[12];
    const float* trans  = (const float*)d_in[13];
    float* out = (float*)d_out;

    float* ws    = (float*)d_ws;
    float* pre_f = ws;                                   // T*G floats
    float* pre_b = pre_f + (size_t)TT * GG;
    float* hs_f  = pre_b + (size_t)TT * GG;              // T*H
    float* hs_b  = hs_f + (size_t)TT * HH;
    float* feats = hs_b + (size_t)TT * HH;               // T*K
    float* hbuf  = feats + (size_t)TT * KK;              // 2*2*H
    int*   cnt   = (int*)(hbuf + 4 * HH);                // 2*T*32 ints

    hipMemsetAsync(cnt, 0, (size_t)2 * TT * 32 * sizeof(int), stream);
    gemm_pre<<<dim3(16, 16, 2), 256, 0, stream>>>(
        embeds, Wihf, bihf, bhhf, Wihb, bihb, bhhb, pre_f, pre_b);
    lstm_scan<<<64, 512, 0, stream>>>(
        Whhf, Whhb, h0, c0, pre_f, pre_b, hs_f, hs_b, hbuf, cnt);
    feats_k<<<TT / 4, 256, 0, stream>>>(hs_f, hs_b, Wout, bout, feats);
    viterbi_k<<<1, 64, 0, stream>>>(feats, trans, out);
}